// Round 1
// baseline (3950.282 us; speedup 1.0000x reference)
//
#include <hip/hip_runtime.h>

// LSTM_84344567759011: 3-layer LSTM (B=16384, T=200, F=10, H=30) + FC(30->1), fp32.
//
// Strategy: one fused persistent kernel. 256 blocks x 512 threads; each block
// owns 64 batch elements for all 200 steps and all 3 layers. Per time step:
// 3x (GEMM phase -> barrier -> gate-update phase -> barrier).
//   GEMM:  wave w (of 8) computes padded gate rows [16w,16w+16) for lane's
//          batch elem b. Operand vector in VGPRs (loaded from LDS, conflict-
//          free 33-float row pitch). Weights indexed wave-uniformly -> s_load
//          on scalar pipe; VALU does pure FMAs (4 parallel chains/row).
//   UPDATE: thread (w,b) owns hidden units [4w,4w+4) c-state in registers;
//          sigmoid/tanh via v_exp_f32 + v_rcp_f32.
// Gates padded 120->128 (pad weights/bias = 0 -> benign zero outputs).

#define LOG2E 1.44269504088896340736f

static constexpr int B = 16384;
static constexpr int T = 200;
static constexpr int F = 10;
static constexpr int H = 30;

// Packed, padded weights in a device-global scratch (filled by prep kernel):
// W1: [128][40]  ([Wih1 | Whh1] rows padded per gate-type to 32)
// W2: [128][60]  ([Wih2 | Whh2])
// W3: [128][60]  ([Wih3 | Whh3])
// b1,b2,b3: [128] (bih+bhh, pad 0), Wfc[30], bfc[1]
static constexpr int W1_OFF = 0;
static constexpr int W2_OFF = 5120;
static constexpr int W3_OFF = 12800;
static constexpr int B1_OFF = 20480;
static constexpr int B2_OFF = 20608;
static constexpr int B3_OFF = 20736;
static constexpr int WFC_OFF = 20864;
static constexpr int BFC_OFF = 20894;

__device__ float g_w[20896];

__global__ void lstm_prep(const float* __restrict__ Wih1, const float* __restrict__ Whh1,
                          const float* __restrict__ bih1, const float* __restrict__ bhh1,
                          const float* __restrict__ Wih2, const float* __restrict__ Whh2,
                          const float* __restrict__ bih2, const float* __restrict__ bhh2,
                          const float* __restrict__ Wih3, const float* __restrict__ Whh3,
                          const float* __restrict__ bih3, const float* __restrict__ bhh3,
                          const float* __restrict__ Wfc, const float* __restrict__ bfc) {
  const int tid = threadIdx.x;  // 256 threads, 1 block
  // W1: 128 rows x 40 cols
  for (int idx = tid; idx < 128 * 40; idx += 256) {
    int r = idx / 40, k = idx - r * 40;
    int q = r >> 5, j = r & 31;
    float v = 0.f;
    if (j < H) {
      int sr = q * H + j;
      v = (k < F) ? Wih1[sr * F + k] : Whh1[sr * H + (k - F)];
    }
    g_w[W1_OFF + idx] = v;
  }
  // W2, W3: 128 rows x 60 cols
  for (int idx = tid; idx < 128 * 60; idx += 256) {
    int r = idx / 60, k = idx - r * 60;
    int q = r >> 5, j = r & 31;
    float v2 = 0.f, v3 = 0.f;
    if (j < H) {
      int sr = q * H + j;
      v2 = (k < H) ? Wih2[sr * H + k] : Whh2[sr * H + (k - H)];
      v3 = (k < H) ? Wih3[sr * H + k] : Whh3[sr * H + (k - H)];
    }
    g_w[W2_OFF + idx] = v2;
    g_w[W3_OFF + idx] = v3;
  }
  // biases
  for (int idx = tid; idx < 128; idx += 256) {
    int q = idx >> 5, j = idx & 31;
    float v1 = 0.f, v2 = 0.f, v3 = 0.f;
    if (j < H) {
      int sr = q * H + j;
      v1 = bih1[sr] + bhh1[sr];
      v2 = bih2[sr] + bhh2[sr];
      v3 = bih3[sr] + bhh3[sr];
    }
    g_w[B1_OFF + idx] = v1;
    g_w[B2_OFF + idx] = v2;
    g_w[B3_OFF + idx] = v3;
  }
  if (tid < H) g_w[WFC_OFF + tid] = Wfc[tid];
  if (tid == 0) g_w[BFC_OFF] = bfc[0];
}

__device__ __forceinline__ float sigx(float x) {
  return __builtin_amdgcn_rcpf(1.f + __builtin_amdgcn_exp2f(-x * LOG2E));
}
__device__ __forceinline__ float tanhx(float x) {
  float e = __builtin_amdgcn_exp2f(-x * (2.f * LOG2E));
  return fmaf(2.f, __builtin_amdgcn_rcpf(1.f + e), -1.f);
}

// GEMM phase: 16 rows per wave, K operand length, 4 parallel FMA chains.
#define DO_GEMM(WOFF, BOFF, K)                                         \
  {                                                                    \
    for (int r = 0; r < 16; ++r) {                                     \
      const int row = wv * 16 + r; /* wave-uniform */                  \
      const float* wr = &g_w[(WOFF) + row * (K)];                      \
      float a0 = g_w[(BOFF) + row], a1 = 0.f, a2 = 0.f, a3 = 0.f;      \
      _Pragma("unroll")                                                \
      for (int k = 0; k < (K); k += 4) {                               \
        a0 = fmaf(wr[k + 0], hop[k + 0], a0);                          \
        a1 = fmaf(wr[k + 1], hop[k + 1], a1);                          \
        a2 = fmaf(wr[k + 2], hop[k + 2], a2);                          \
        a3 = fmaf(wr[k + 3], hop[k + 3], a3);                          \
      }                                                                \
      z_s[b * 129 + row] = (a0 + a1) + (a2 + a3);                      \
    }                                                                  \
  }

// Update phase: 4 hidden units per thread, c-state in carr[4].
#define DO_UPDATE(carr, L)                                             \
  {                                                                    \
    const int j0 = wv * 4;                                             \
    _Pragma("unroll")                                                  \
    for (int jj = 0; jj < 4; ++jj) {                                   \
      const int j = j0 + jj;                                           \
      float zi = z_s[b * 129 + j];                                     \
      float zf = z_s[b * 129 + 32 + j];                                \
      float zg = z_s[b * 129 + 64 + j];                                \
      float zo = z_s[b * 129 + 96 + j];                                \
      float ii = sigx(zi), ff = sigx(zf);                              \
      float gg = tanhx(zg), oo = sigx(zo);                             \
      float cc = fmaf(ff, carr[jj], ii * gg);                          \
      carr[jj] = cc;                                                   \
      h_s[L][b * 33 + j] = oo * tanhx(cc);                             \
    }                                                                  \
  }

__global__ __launch_bounds__(512, 2) void lstm_main(const float* __restrict__ x,
                                                    float* __restrict__ out) {
  __shared__ float z_s[64 * 129];     // [b][128 padded gate rows], pitch 129
  __shared__ float h_s[3][64 * 33];   // [layer][b][30 h + pad], pitch 33

  const int tid = threadIdx.x;
  const int b = tid & 63;                                        // batch lane
  const int wv = __builtin_amdgcn_readfirstlane(tid >> 6);       // wave 0..7
  const int b0 = blockIdx.x * 64;

  for (int i = tid; i < 64 * 33; i += 512) {
    h_s[0][i] = 0.f;
    h_s[1][i] = 0.f;
    h_s[2][i] = 0.f;
  }
  float c1[4] = {0.f, 0.f, 0.f, 0.f};
  float c2[4] = {0.f, 0.f, 0.f, 0.f};
  float c3[4] = {0.f, 0.f, 0.f, 0.f};

  const float* xb = x + (size_t)(b0 + b) * (T * F);
  float xv[F];
#pragma unroll
  for (int i = 0; i < 5; ++i) {
    float2 t2 = *(const float2*)(xb + i * 2);
    xv[2 * i] = t2.x;
    xv[2 * i + 1] = t2.y;
  }

  __syncthreads();

  for (int t = 0; t < T; ++t) {
    float hop[60];
    // ---- L1 GEMM: hop = [x(10) | h1(30)], K=40
#pragma unroll
    for (int i = 0; i < F; ++i) hop[i] = xv[i];
#pragma unroll
    for (int k = 0; k < H; ++k) hop[F + k] = h_s[0][b * 33 + k];
    DO_GEMM(W1_OFF, B1_OFF, 40);

    // prefetch next timestep's x while L1 z settles
    if (t + 1 < T) {
#pragma unroll
      for (int i = 0; i < 5; ++i) {
        float2 t2 = *(const float2*)(xb + (t + 1) * F + i * 2);
        xv[2 * i] = t2.x;
        xv[2 * i + 1] = t2.y;
      }
    }
    __syncthreads();
    DO_UPDATE(c1, 0);
    __syncthreads();

    // ---- L2 GEMM: hop = [h1(30) | h2(30)], K=60
#pragma unroll
    for (int k = 0; k < H; ++k) hop[k] = h_s[0][b * 33 + k];
#pragma unroll
    for (int k = 0; k < H; ++k) hop[H + k] = h_s[1][b * 33 + k];
    DO_GEMM(W2_OFF, B2_OFF, 60);
    __syncthreads();
    DO_UPDATE(c2, 1);
    __syncthreads();

    // ---- L3 GEMM: hop = [h2(30) | h3(30)], K=60
#pragma unroll
    for (int k = 0; k < H; ++k) hop[k] = h_s[1][b * 33 + k];
#pragma unroll
    for (int k = 0; k < H; ++k) hop[H + k] = h_s[2][b * 33 + k];
    DO_GEMM(W3_OFF, B3_OFF, 60);
    __syncthreads();
    DO_UPDATE(c3, 2);
    __syncthreads();
  }

  // ---- FC epilogue: out[b] = h3 . Wfc + bfc (wave 0 only)
  if (wv == 0) {
    float acc = g_w[BFC_OFF];
#pragma unroll
    for (int k = 0; k < H; ++k) acc = fmaf(h_s[2][b * 33 + k], g_w[WFC_OFF + k], acc);
    out[b0 + b] = acc;
  }
}

extern "C" void kernel_launch(void* const* d_in, const int* in_sizes, int n_in,
                              void* d_out, int out_size, void* d_ws, size_t ws_size,
                              hipStream_t stream) {
  const float* x = (const float*)d_in[0];
  const float* Wih1 = (const float*)d_in[1];
  const float* Whh1 = (const float*)d_in[2];
  const float* bih1 = (const float*)d_in[3];
  const float* bhh1 = (const float*)d_in[4];
  const float* Wih2 = (const float*)d_in[5];
  const float* Whh2 = (const float*)d_in[6];
  const float* bih2 = (const float*)d_in[7];
  const float* bhh2 = (const float*)d_in[8];
  const float* Wih3 = (const float*)d_in[9];
  const float* Whh3 = (const float*)d_in[10];
  const float* bih3 = (const float*)d_in[11];
  const float* bhh3 = (const float*)d_in[12];
  const float* Wfc = (const float*)d_in[13];
  const float* bfc = (const float*)d_in[14];
  float* out = (float*)d_out;

  hipLaunchKernelGGL(lstm_prep, dim3(1), dim3(256), 0, stream,
                     Wih1, Whh1, bih1, bhh1, Wih2, Whh2, bih2, bhh2,
                     Wih3, Whh3, bih3, bhh3, Wfc, bfc);
  hipLaunchKernelGGL(lstm_main, dim3(B / 64), dim3(512), 0, stream, x, out);
}

// Round 2
// 1981.211 us; speedup vs baseline: 1.9939x; 1.9939x over previous
//
#include <hip/hip_runtime.h>

// LSTM_84344567759011: 3-layer LSTM (B=16384, T=200, F=10, H=30) + FC(30->1), fp32.
//
// Round 2: 256 blocks x 1024 threads (16 waves). Block owns 64 batch elems
// (lane = batch). Weight rows re-packed so wave w owns complete units
// {2w, 2w+1}: packed row = w*8 + {i0,i1,f0,f1,g0,g1,o0,o1}. Gate pre-acts z
// stay in registers -> update is thread-local right after the GEMM; only the
// 30-float h vector goes through LDS (double-buffered by t parity).
// 3 barriers/step (was 6). Weights streamed on the scalar pipe (wave-uniform
// row addresses via readfirstlane'd wave id).

#define LOG2E 1.44269504088896340736f

static constexpr int B = 16384;
static constexpr int T = 200;
static constexpr int F = 10;
static constexpr int H = 30;

// Packed weights in device-global scratch (filled by prep kernel):
// W1: [128][40] rows packed per-wave-unit; W2,W3: [128][60]; b1,b2,b3: [128]
static constexpr int W1_OFF = 0;
static constexpr int W2_OFF = 5120;
static constexpr int W3_OFF = 12800;
static constexpr int B1_OFF = 20480;
static constexpr int B2_OFF = 20608;
static constexpr int B3_OFF = 20736;
static constexpr int WFC_OFF = 20864;
static constexpr int BFC_OFF = 20894;

__device__ float g_w[20896];

// packed row pr (0..127): wave wv = pr>>3, idx = pr&7, gate = idx>>1, u = idx&1
// source unit j = wv*2+u (valid if j<30), source row sr = gate*30 + j.
__global__ void lstm_prep(const float* __restrict__ Wih1, const float* __restrict__ Whh1,
                          const float* __restrict__ bih1, const float* __restrict__ bhh1,
                          const float* __restrict__ Wih2, const float* __restrict__ Whh2,
                          const float* __restrict__ bih2, const float* __restrict__ bhh2,
                          const float* __restrict__ Wih3, const float* __restrict__ Whh3,
                          const float* __restrict__ bih3, const float* __restrict__ bhh3,
                          const float* __restrict__ Wfc, const float* __restrict__ bfc) {
  const int tid = threadIdx.x;  // 256 threads, 1 block
  // W1: 128 rows x 40 cols ([Wih1(10) | Whh1(30)])
  for (int idx = tid; idx < 128 * 40; idx += 256) {
    int pr = idx / 40, k = idx - pr * 40;
    int wv = pr >> 3, g = (pr >> 1) & 3, u = pr & 1;
    int j = wv * 2 + u;
    float v = 0.f;
    if (j < H) {
      int sr = g * H + j;
      v = (k < F) ? Wih1[sr * F + k] : Whh1[sr * H + (k - F)];
    }
    g_w[W1_OFF + idx] = v;
  }
  // W2, W3: 128 rows x 60 cols ([Wih(30) | Whh(30)])
  for (int idx = tid; idx < 128 * 60; idx += 256) {
    int pr = idx / 60, k = idx - pr * 60;
    int wv = pr >> 3, g = (pr >> 1) & 3, u = pr & 1;
    int j = wv * 2 + u;
    float v2 = 0.f, v3 = 0.f;
    if (j < H) {
      int sr = g * H + j;
      v2 = (k < H) ? Wih2[sr * H + k] : Whh2[sr * H + (k - H)];
      v3 = (k < H) ? Wih3[sr * H + k] : Whh3[sr * H + (k - H)];
    }
    g_w[W2_OFF + idx] = v2;
    g_w[W3_OFF + idx] = v3;
  }
  // biases (same packed-row order)
  for (int pr = tid; pr < 128; pr += 256) {
    int wv = pr >> 3, g = (pr >> 1) & 3, u = pr & 1;
    int j = wv * 2 + u;
    float v1 = 0.f, v2 = 0.f, v3 = 0.f;
    if (j < H) {
      int sr = g * H + j;
      v1 = bih1[sr] + bhh1[sr];
      v2 = bih2[sr] + bhh2[sr];
      v3 = bih3[sr] + bhh3[sr];
    }
    g_w[B1_OFF + pr] = v1;
    g_w[B2_OFF + pr] = v2;
    g_w[B3_OFF + pr] = v3;
  }
  if (tid < H) g_w[WFC_OFF + tid] = Wfc[tid];
  if (tid == 0) g_w[BFC_OFF] = bfc[0];
}

__device__ __forceinline__ float sigx(float x) {
  return __builtin_amdgcn_rcpf(1.f + __builtin_amdgcn_exp2f(-x * LOG2E));
}
__device__ __forceinline__ float tanhx(float x) {
  float e = __builtin_amdgcn_exp2f(-x * (2.f * LOG2E));
  return fmaf(2.f, __builtin_amdgcn_rcpf(1.f + e), -1.f);
}

// One layer phase: GEMM (8 packed rows, z in regs) + thread-local gate update.
// K = 40 (L1: [x|h_own]) or 60 ([h_prev|h_own]).
template <int K, bool FIRST>
__device__ __forceinline__ void phase(const float* __restrict__ win,
                                      const float* __restrict__ bin,
                                      const float* xv,
                                      const float* __restrict__ hprev_lds,
                                      const float* __restrict__ hown_lds,
                                      float* __restrict__ hout_lds,
                                      float* c, int wv) {
  float hop[K];
#pragma unroll
  for (int k = 0; k < K - H; ++k) hop[k] = FIRST ? xv[k] : hprev_lds[k];
#pragma unroll
  for (int k = 0; k < H; ++k) hop[K - H + k] = hown_lds[k];

  float z[8];
  const float* wb = win + (wv * 8) * K;  // wave-uniform -> scalar loads
#pragma unroll
  for (int r = 0; r < 8; ++r) {
    const float* wr = wb + r * K;
    float a0 = bin[wv * 8 + r], a1 = 0.f;
#pragma unroll
    for (int k = 0; k < K; k += 2) {
      a0 = fmaf(wr[k], hop[k], a0);
      a1 = fmaf(wr[k + 1], hop[k + 1], a1);
    }
    z[r] = a0 + a1;
  }
#pragma unroll
  for (int u = 0; u < 2; ++u) {
    float ii = sigx(z[u]);
    float ff = sigx(z[2 + u]);
    float gg = tanhx(z[4 + u]);
    float oo = sigx(z[6 + u]);
    float cc = fmaf(ff, c[u], ii * gg);
    c[u] = cc;
    hout_lds[wv * 2 + u] = oo * tanhx(cc);
  }
}

__global__ __launch_bounds__(1024, 4) void lstm_main(const float* __restrict__ x,
                                                     float* __restrict__ out) {
  __shared__ float h_s[3][2][64 * 33];  // [layer][t-parity][b][30 h + pad], pitch 33

  const int tid = threadIdx.x;
  const int b = tid & 63;                                   // batch lane
  const int wv = __builtin_amdgcn_readfirstlane(tid >> 6);  // wave 0..15
  const int b0 = blockIdx.x * 64;

  for (int i = tid; i < 2 * 64 * 33; i += 1024) {
    h_s[0][0][i] = 0.f;
    h_s[1][0][i] = 0.f;
    h_s[2][0][i] = 0.f;
  }
  float c1[2] = {0.f, 0.f};
  float c2[2] = {0.f, 0.f};
  float c3[2] = {0.f, 0.f};

  const float* xb = x + (size_t)(b0 + b) * (T * F);
  float xv[F];
#pragma unroll
  for (int i = 0; i < 5; ++i) {
    float2 t2 = *(const float2*)(xb + i * 2);
    xv[2 * i] = t2.x;
    xv[2 * i + 1] = t2.y;
  }

  __syncthreads();

  for (int t = 0; t < T; ++t) {
    const int rp = t & 1, wp = rp ^ 1;
    // ---- L1: hop = [x(10) | h1(30)]
    phase<40, true>(g_w + W1_OFF, g_w + B1_OFF, xv,
                    nullptr, &h_s[0][rp][b * 33], &h_s[0][wp][b * 33], c1, wv);
    // prefetch next timestep's x (dead xv regs after phase consumed them)
    if (t + 1 < T) {
#pragma unroll
      for (int i = 0; i < 5; ++i) {
        float2 t2 = *(const float2*)(xb + (t + 1) * F + i * 2);
        xv[2 * i] = t2.x;
        xv[2 * i + 1] = t2.y;
      }
    }
    __syncthreads();
    // ---- L2: hop = [h1_new(30) | h2(30)]
    phase<60, false>(g_w + W2_OFF, g_w + B2_OFF, nullptr,
                     &h_s[0][wp][b * 33], &h_s[1][rp][b * 33], &h_s[1][wp][b * 33], c2, wv);
    __syncthreads();
    // ---- L3: hop = [h2_new(30) | h3(30)]
    phase<60, false>(g_w + W3_OFF, g_w + B3_OFF, nullptr,
                     &h_s[1][wp][b * 33], &h_s[2][rp][b * 33], &h_s[2][wp][b * 33], c3, wv);
    __syncthreads();
  }

  // ---- FC epilogue: out[b] = h3 . Wfc + bfc. Final h3 parity: wp(199) = 0.
  if (wv == 0) {
    float acc = g_w[BFC_OFF];
#pragma unroll
    for (int k = 0; k < H; ++k) acc = fmaf(h_s[2][0][b * 33 + k], g_w[WFC_OFF + k], acc);
    out[b0 + b] = acc;
  }
}

extern "C" void kernel_launch(void* const* d_in, const int* in_sizes, int n_in,
                              void* d_out, int out_size, void* d_ws, size_t ws_size,
                              hipStream_t stream) {
  const float* x = (const float*)d_in[0];
  const float* Wih1 = (const float*)d_in[1];
  const float* Whh1 = (const float*)d_in[2];
  const float* bih1 = (const float*)d_in[3];
  const float* bhh1 = (const float*)d_in[4];
  const float* Wih2 = (const float*)d_in[5];
  const float* Whh2 = (const float*)d_in[6];
  const float* bih2 = (const float*)d_in[7];
  const float* bhh2 = (const float*)d_in[8];
  const float* Wih3 = (const float*)d_in[9];
  const float* Whh3 = (const float*)d_in[10];
  const float* bih3 = (const float*)d_in[11];
  const float* bhh3 = (const float*)d_in[12];
  const float* Wfc = (const float*)d_in[13];
  const float* bfc = (const float*)d_in[14];
  float* out = (float*)d_out;

  hipLaunchKernelGGL(lstm_prep, dim3(1), dim3(256), 0, stream,
                     Wih1, Whh1, bih1, bhh1, Wih2, Whh2, bih2, bhh2,
                     Wih3, Whh3, bih3, bhh3, Wfc, bfc);
  hipLaunchKernelGGL(lstm_main, dim3(B / 64), dim3(1024), 0, stream, x, out);
}